// Round 5
// baseline (738.468 us; speedup 1.0000x reference)
//
#include <hip/hip_runtime.h>

// ---------------------------------------------------------------------------
// GraphSAGE (2x SAGEConv mean + mean-pool + MLP scorer), f32 end-to-end.
// CSR build via two-level counting sort (bucket = dst>>8); rp derived from
// bucket bases + per-bucket LDS scan (no global scan chain). Aggregation:
// wave-per-(node[,half]) gathers with up-front ssrc preload + shfl broadcast
// so gathers issue back-to-back (MLP, not chained latency).
// ---------------------------------------------------------------------------

#define EPB 16384  // edges per block in binning kernels

// per-block LDS histogram of bucket sizes -> global bucket counts
__global__ __launch_bounds__(256) void k_bcnt(const int* __restrict__ dst,
                                              int* __restrict__ bcnt, int E) {
    __shared__ int hist[1024];
    for (int i = threadIdx.x; i < 1024; i += 256) hist[i] = 0;
    __syncthreads();
    int s = blockIdx.x * EPB;
    int e_end = min(s + EPB, E);
    for (int e = s + threadIdx.x; e < e_end; e += 256)
        atomicAdd(&hist[dst[e] >> 8], 1);
    __syncthreads();
    for (int i = threadIdx.x; i < 1024; i += 256)
        if (hist[i]) atomicAdd(&bcnt[i], hist[i]);
}

// exclusive scan of bucket counts (NB <= 1024) -> bbase, mutable btail, rp[N]=E
__global__ void k_bscan(const int* __restrict__ bcnt, int* __restrict__ bbase,
                        int* __restrict__ btail, int* __restrict__ rp,
                        int NB, int N, int E) {
    __shared__ int sm[1024];
    int t = threadIdx.x;
    int v = (t < NB) ? bcnt[t] : 0;
    sm[t] = v;
    __syncthreads();
    for (int off = 1; off < 1024; off <<= 1) {
        int u = (t >= off) ? sm[t - off] : 0;
        __syncthreads();
        sm[t] += u;
        __syncthreads();
    }
    if (t < NB) { int ex = sm[t] - v; bbase[t] = ex; btail[t] = ex; }
    if (t == 0) rp[N] = E;
}

// bin (src,dst) pairs into bucket regions; per-block LDS count -> one global
// atomic per (block,bucket) -> appending, line-local writes
__global__ __launch_bounds__(256) void k_binscatter(
    const int* __restrict__ src, const int* __restrict__ dst,
    int* __restrict__ btail, int2* __restrict__ pairs, int E) {
    __shared__ int hist[1024];
    __shared__ int base[1024];
    int s = blockIdx.x * EPB;
    int e_end = min(s + EPB, E);
    for (int i = threadIdx.x; i < 1024; i += 256) hist[i] = 0;
    __syncthreads();
    for (int e = s + threadIdx.x; e < e_end; e += 256)
        atomicAdd(&hist[dst[e] >> 8], 1);
    __syncthreads();
    for (int i = threadIdx.x; i < 1024; i += 256) {
        int h = hist[i];
        base[i] = h ? atomicAdd(&btail[i], h) : 0;
        hist[i] = 0;  // reuse as local append counter
    }
    __syncthreads();
    for (int e = s + threadIdx.x; e < e_end; e += 256) {
        int d = dst[e];
        int b = d >> 8;
        int pos = base[b] + atomicAdd(&hist[b], 1);
        pairs[pos] = make_int2(src[e], d);
    }
}

// fused: per-bucket histogram -> deg -> LDS scan -> rp/dinv -> place ssrc.
// rp[node] = bbase[bucket] + within-bucket exclusive scan of deg.
__global__ __launch_bounds__(256) void k_build(
    const int2* __restrict__ pairs, const int* __restrict__ bbase,
    const int* __restrict__ bcnt, float* __restrict__ dinv,
    int* __restrict__ rp, int* __restrict__ ssrc, int N) {
    __shared__ int h[256];
    __shared__ int sc[256];
    __shared__ int lcnt[256];
    int b = blockIdx.x, t = threadIdx.x;
    h[t] = 0;
    __syncthreads();
    int s = bbase[b], cntb = bcnt[b];
    for (int i = t; i < cntb; i += 256)
        atomicAdd(&h[pairs[s + i].y & 255], 1);
    __syncthreads();
    int d = h[t];
    sc[t] = d;
    lcnt[t] = 0;
    __syncthreads();
    for (int off = 1; off < 256; off <<= 1) {
        int u = (t >= off) ? sc[t - off] : 0;
        __syncthreads();
        sc[t] += u;
        __syncthreads();
    }
    int abs_ex = s + sc[t] - d;   // absolute CSR start for this node
    int node = b * 256 + t;
    if (node < N) {
        rp[node] = abs_ex;
        dinv[node] = (d > 0) ? 1.0f / (float)d : 0.0f;
    }
    sc[t] = abs_ex;
    __syncthreads();
    for (int i = t; i < cntb; i += 256) {
        int2 p = pairs[s + i];
        int local = p.y & 255;
        int pos = sc[local] + atomicAdd(&lcnt[local], 1);
        ssrc[pos] = p.x;
    }
}

// h0[n][0:32] = emb[node_ids[n]][0:32]; 8 threads (float4 each) per node
__global__ void k_emb(const int* __restrict__ ids, const float* __restrict__ emb,
                      float* __restrict__ h0, int n) {
    int t = blockIdx.x * 256 + threadIdx.x;
    int node = t >> 3, q = t & 7;
    if (node >= n) return;
    size_t id = (size_t)ids[node];
    *(float4*)(h0 + (size_t)node * 32 + q * 4) =
        *(const float4*)(emb + id * 32 + q * 4);
}

// mean-agg 32-wide rows: one wave per node; ssrc preloaded (1 coalesced load),
// then 8 edges x 8 lanes(float4) per iter with shfl-broadcast src indices.
__global__ __launch_bounds__(256) void k_agg32(
    const float* __restrict__ h, const int* __restrict__ rp,
    const int* __restrict__ ssrc, const float* __restrict__ dinv,
    float* __restrict__ agg, int n) {
    int node = (blockIdx.x * 256 + threadIdx.x) >> 6;
    int lane = threadIdx.x & 63;
    if (node >= n) return;
    int start = rp[node];
    int deg = rp[node + 1] - start;
    int eo = lane >> 3, q = lane & 7;
    int sidx = (lane < deg) ? ssrc[start + lane] : 0;
    int npre = min(deg, 64);
    float4 acc = {0.f, 0.f, 0.f, 0.f};
    const float* hb = h + q * 4;
    for (int g = 0; g * 8 < npre; ++g) {
        int ei = g * 8 + eo;
        int s = __shfl(sidx, ei);
        if (ei < npre) {
            float4 v = *(const float4*)(hb + (size_t)s * 32);
            acc.x += v.x; acc.y += v.y; acc.z += v.z; acc.w += v.w;
        }
    }
    for (int e = start + 64 + eo; e < start + deg; e += 8) {  // rare tail
        int s = ssrc[e];
        float4 v = *(const float4*)(hb + (size_t)s * 32);
        acc.x += v.x; acc.y += v.y; acc.z += v.z; acc.w += v.w;
    }
    for (int m = 8; m < 64; m <<= 1) {
        acc.x += __shfl_xor(acc.x, m);
        acc.y += __shfl_xor(acc.y, m);
        acc.z += __shfl_xor(acc.z, m);
        acc.w += __shfl_xor(acc.w, m);
    }
    if (lane < 8) {
        float di = dinv[node];
        float4 o = {acc.x * di, acc.y * di, acc.z * di, acc.w * di};
        *(float4*)(agg + (size_t)node * 32 + q * 4) = o;
    }
}

// mean-agg 64-wide rows: one wave per (node, 32-feat half) -> 2x waves,
// 8 edges x 8 lanes per iter, ssrc preload + shfl broadcast.
__global__ __launch_bounds__(256) void k_agg64(
    const float* __restrict__ h, const int* __restrict__ rp,
    const int* __restrict__ ssrc, const float* __restrict__ dinv,
    float* __restrict__ agg, int n) {
    int gw = (blockIdx.x * 256 + threadIdx.x) >> 6;
    int node = gw >> 1, half = gw & 1;
    if (node >= n) return;
    int lane = threadIdx.x & 63;
    int start = rp[node];
    int deg = rp[node + 1] - start;
    int eo = lane >> 3, q = lane & 7;
    int sidx = (lane < deg) ? ssrc[start + lane] : 0;
    int npre = min(deg, 64);
    float4 acc = {0.f, 0.f, 0.f, 0.f};
    const float* hb = h + half * 32 + q * 4;
    for (int g = 0; g * 8 < npre; ++g) {
        int ei = g * 8 + eo;
        int s = __shfl(sidx, ei);
        if (ei < npre) {
            float4 v = *(const float4*)(hb + (size_t)s * 64);
            acc.x += v.x; acc.y += v.y; acc.z += v.z; acc.w += v.w;
        }
    }
    for (int e = start + 64 + eo; e < start + deg; e += 8) {  // rare tail
        int s = ssrc[e];
        float4 v = *(const float4*)(hb + (size_t)s * 64);
        acc.x += v.x; acc.y += v.y; acc.z += v.z; acc.w += v.w;
    }
    for (int m = 8; m < 64; m <<= 1) {
        acc.x += __shfl_xor(acc.x, m);
        acc.y += __shfl_xor(acc.y, m);
        acc.z += __shfl_xor(acc.z, m);
        acc.w += __shfl_xor(acc.w, m);
    }
    if (lane < 8) {
        float di = dinv[node];
        float4 o = {acc.x * di, acc.y * di, acc.z * di, acc.w * di};
        *(float4*)(agg + (size_t)node * 64 + half * 32 + q * 4) = o;
    }
}

// out[n][64] = relu(x[n][:K] @ Ws + a[n][:K] @ Wn + b); thread = node.
template <int K>
__global__ __launch_bounds__(256) void k_dense(
    const float* __restrict__ x, const float* __restrict__ a,
    const float* __restrict__ Wsg, const float* __restrict__ Wng,
    const float* __restrict__ bg, float* __restrict__ out, int n) {
    __shared__ float ws[K * 64];
    __shared__ float wn[K * 64];
    __shared__ float bs[64];
    for (int i = threadIdx.x; i < K * 64; i += 256) { ws[i] = Wsg[i]; wn[i] = Wng[i]; }
    if (threadIdx.x < 64) bs[threadIdx.x] = bg[threadIdx.x];
    __syncthreads();
    int node = blockIdx.x * 256 + threadIdx.x;
    if (node >= n) return;
    float xr[K], ar[K];
#pragma unroll
    for (int q = 0; q < K / 4; ++q) {
        float4 v = *(const float4*)(x + (size_t)node * K + q * 4);
        xr[q * 4 + 0] = v.x; xr[q * 4 + 1] = v.y; xr[q * 4 + 2] = v.z; xr[q * 4 + 3] = v.w;
        float4 u = *(const float4*)(a + (size_t)node * K + q * 4);
        ar[q * 4 + 0] = u.x; ar[q * 4 + 1] = u.y; ar[q * 4 + 2] = u.z; ar[q * 4 + 3] = u.w;
    }
    float* op = out + (size_t)node * 64;
#pragma unroll 1
    for (int jt = 0; jt < 8; ++jt) {
        float acc0 = bs[jt * 8 + 0], acc1 = bs[jt * 8 + 1], acc2 = bs[jt * 8 + 2], acc3 = bs[jt * 8 + 3];
        float acc4 = bs[jt * 8 + 4], acc5 = bs[jt * 8 + 5], acc6 = bs[jt * 8 + 6], acc7 = bs[jt * 8 + 7];
#pragma unroll
        for (int k = 0; k < K; ++k) {
            float4 w0 = *(const float4*)&ws[k * 64 + jt * 8];
            float4 w1 = *(const float4*)&ws[k * 64 + jt * 8 + 4];
            acc0 += xr[k] * w0.x; acc1 += xr[k] * w0.y; acc2 += xr[k] * w0.z; acc3 += xr[k] * w0.w;
            acc4 += xr[k] * w1.x; acc5 += xr[k] * w1.y; acc6 += xr[k] * w1.z; acc7 += xr[k] * w1.w;
            float4 v0 = *(const float4*)&wn[k * 64 + jt * 8];
            float4 v1 = *(const float4*)&wn[k * 64 + jt * 8 + 4];
            acc0 += ar[k] * v0.x; acc1 += ar[k] * v0.y; acc2 += ar[k] * v0.z; acc3 += ar[k] * v0.w;
            acc4 += ar[k] * v1.x; acc5 += ar[k] * v1.y; acc6 += ar[k] * v1.z; acc7 += ar[k] * v1.w;
        }
        float4 o0 = {fmaxf(acc0, 0.f), fmaxf(acc1, 0.f), fmaxf(acc2, 0.f), fmaxf(acc3, 0.f)};
        float4 o1 = {fmaxf(acc4, 0.f), fmaxf(acc5, 0.f), fmaxf(acc6, 0.f), fmaxf(acc7, 0.f)};
        *(float4*)(op + jt * 8) = o0;
        *(float4*)(op + jt * 8 + 4) = o1;
    }
}

// graph boundaries via binary search (graph_ids is sorted)
__global__ void k_bounds(const int* __restrict__ gid, int* __restrict__ starts,
                         int n, int B) {
    int b = blockIdx.x * 256 + threadIdx.x;
    if (b > B) return;
    if (b == B) { starts[B] = n; return; }
    int lo = 0, hi = n;
    while (lo < hi) {
        int mid = (lo + hi) >> 1;
        if (gid[mid] < b) lo = mid + 1; else hi = mid;
    }
    starts[b] = lo;
}

// per-graph mean over node range; block per graph, 4 rows x 64 feats
__global__ void k_pool(const float* __restrict__ h2, const int* __restrict__ starts,
                       float* __restrict__ hg, int B) {
    __shared__ float sm[256];
    int b = blockIdx.x;
    int t = threadIdx.x, j = t & 63, r = t >> 6;
    int s = starts[b], e = starts[b + 1];
    float acc = 0.f;
    for (int nn = s + r; nn < e; nn += 4) acc += h2[(size_t)nn * 64 + j];
    sm[t] = acc;
    __syncthreads();
    if (t < 64) {
        float v = sm[t] + sm[t + 64] + sm[t + 128] + sm[t + 192];
        float cntf = (float)(e - s);
        hg[b * 64 + j] = v / fmaxf(cntf, 1.0f);
    }
}

// scorer: relu(hg @ Ws1 + bs1) @ Ws2 + bs2 ; block per graph, 64 lanes
__global__ void k_score(const float* __restrict__ hg, const float* __restrict__ Ws1,
                        const float* __restrict__ bs1, const float* __restrict__ Ws2,
                        const float* __restrict__ bs2, float* __restrict__ out, int B) {
    int b = blockIdx.x;
    int j = threadIdx.x;  // 64 threads
    const float* hrow = hg + b * 64;
    float acc = bs1[j];
    for (int k = 0; k < 64; ++k) acc += hrow[k] * Ws1[k * 64 + j];
    float t = fmaxf(acc, 0.f) * Ws2[j];
    for (int m = 1; m < 64; m <<= 1) t += __shfl_xor(t, m);
    if (j == 0) out[b] = t + bs2[0];
}

extern "C" void kernel_launch(void* const* d_in, const int* in_sizes, int n_in,
                              void* d_out, int out_size, void* d_ws, size_t ws_size,
                              hipStream_t stream) {
    const int*   node_ids = (const int*)d_in[0];
    const int*   src      = (const int*)d_in[1];
    const int*   dst      = (const int*)d_in[2];
    const int*   gid      = (const int*)d_in[3];
    const float* emb      = (const float*)d_in[4];
    const float* Ws1      = (const float*)d_in[5];
    const float* Wn1      = (const float*)d_in[6];
    const float* b1       = (const float*)d_in[7];
    const float* Ws2      = (const float*)d_in[8];
    const float* Wn2      = (const float*)d_in[9];
    const float* b2       = (const float*)d_in[10];
    const float* Ms1      = (const float*)d_in[11];
    const float* mb1      = (const float*)d_in[12];
    const float* Ms2      = (const float*)d_in[13];
    const float* mb2      = (const float*)d_in[14];
    float* out = (float*)d_out;

    int N = in_sizes[0];
    int E = in_sizes[1];
    int B = out_size;
    int NB = (N + 255) >> 8;          // dst buckets (<=1024)

    char* w = (char*)d_ws;
    size_t off = 0;
    auto take = [&](size_t bytes) -> void* {
        void* p = (void*)(w + off);
        off += (bytes + 255) & ~(size_t)255;
        return p;
    };
    int*   rp     = (int*)take((size_t)(N + 1) * 4);
    float* dinv   = (float*)take((size_t)N * 4);
    int*   ssrc   = (int*)take((size_t)E * 4);
    int*   bcnt   = (int*)take(1024 * 4);
    int*   bbase  = (int*)take(1024 * 4);
    int*   btail  = (int*)take(1024 * 4);
    float* h0     = (float*)take((size_t)N * 64 * 4);   // layer-1 input (stride 32), reused as h2 (stride 64)
    float* h1     = (float*)take((size_t)N * 64 * 4);
    float* agg    = (float*)take((size_t)N * 64 * 4);   // reused: stride 32 then 64
    int*   starts = (int*)take((size_t)(B + 1) * 4);
    float* hg     = (float*)take((size_t)B * 64 * 4);
    int2*  pairs  = (int2*)agg;       // alias: pairs dead before k_agg32 writes agg

    int nbeb = (E + EPB - 1) / EPB;

    hipMemsetAsync(bcnt, 0, (size_t)NB * 4, stream);
    k_bcnt<<<nbeb, 256, 0, stream>>>(dst, bcnt, E);
    k_bscan<<<1, 1024, 0, stream>>>(bcnt, bbase, btail, rp, NB, N, E);
    k_binscatter<<<nbeb, 256, 0, stream>>>(src, dst, btail, pairs, E);
    k_build<<<NB, 256, 0, stream>>>(pairs, bbase, bcnt, dinv, rp, ssrc, N);

    k_emb<<<(N * 8 + 255) / 256, 256, 0, stream>>>(node_ids, emb, h0, N);

    // layer 1: agg over h0 (32-wide), dense 32->64
    k_agg32<<<(N + 3) / 4, 256, 0, stream>>>(h0, rp, ssrc, dinv, agg, N);
    k_dense<32><<<(N + 255) / 256, 256, 0, stream>>>(h0, agg, Ws1, Wn1, b1, h1, N);

    // layer 2: agg over h1 (64-wide), dense 64->64 (h2 reuses h0 buffer)
    k_agg64<<<(2 * N + 3) / 4, 256, 0, stream>>>(h1, rp, ssrc, dinv, agg, N);
    k_dense<64><<<(N + 255) / 256, 256, 0, stream>>>(h1, agg, Ws2, Wn2, b2, h0, N);

    // pooling + scorer
    k_bounds<<<(B + 1 + 255) / 256, 256, 0, stream>>>(gid, starts, N, B);
    k_pool<<<B, 256, 0, stream>>>(h0, starts, hg, B);
    k_score<<<B, 64, 0, stream>>>(hg, Ms1, mb1, Ms2, mb2, out, B);
}

// Round 6
// 721.944 us; speedup vs baseline: 1.0229x; 1.0229x over previous
//
#include <hip/hip_runtime.h>

// ---------------------------------------------------------------------------
// GraphSAGE (2x SAGEConv mean + mean-pool + MLP scorer), f32 end-to-end.
// CSR build via two-level counting sort (bucket = dst>>8); rp derived from
// bucket bases + per-bucket LDS scan. Aggregation: wave-per-node gathers,
// manually unrolled with independent accumulators so 4 gathers (16 edges)
// are in flight per wave before any waitcnt (MLP=4, was 1).
// ---------------------------------------------------------------------------

#define EPB 16384  // edges per block in binning kernels

// per-block LDS histogram of bucket sizes -> global bucket counts
__global__ __launch_bounds__(256) void k_bcnt(const int* __restrict__ dst,
                                              int* __restrict__ bcnt, int E) {
    __shared__ int hist[1024];
    for (int i = threadIdx.x; i < 1024; i += 256) hist[i] = 0;
    __syncthreads();
    int s = blockIdx.x * EPB;
    int e_end = min(s + EPB, E);
    for (int e = s + threadIdx.x; e < e_end; e += 256)
        atomicAdd(&hist[dst[e] >> 8], 1);
    __syncthreads();
    for (int i = threadIdx.x; i < 1024; i += 256)
        if (hist[i]) atomicAdd(&bcnt[i], hist[i]);
}

// exclusive scan of bucket counts (NB <= 1024) -> bbase, mutable btail, rp[N]=E
__global__ void k_bscan(const int* __restrict__ bcnt, int* __restrict__ bbase,
                        int* __restrict__ btail, int* __restrict__ rp,
                        int NB, int N, int E) {
    __shared__ int sm[1024];
    int t = threadIdx.x;
    int v = (t < NB) ? bcnt[t] : 0;
    sm[t] = v;
    __syncthreads();
    for (int off = 1; off < 1024; off <<= 1) {
        int u = (t >= off) ? sm[t - off] : 0;
        __syncthreads();
        sm[t] += u;
        __syncthreads();
    }
    if (t < NB) { int ex = sm[t] - v; bbase[t] = ex; btail[t] = ex; }
    if (t == 0) rp[N] = E;
}

// bin (src,dst) pairs into bucket regions; per-block LDS count -> one global
// atomic per (block,bucket) -> appending, line-local writes
__global__ __launch_bounds__(256) void k_binscatter(
    const int* __restrict__ src, const int* __restrict__ dst,
    int* __restrict__ btail, int2* __restrict__ pairs, int E) {
    __shared__ int hist[1024];
    __shared__ int base[1024];
    int s = blockIdx.x * EPB;
    int e_end = min(s + EPB, E);
    for (int i = threadIdx.x; i < 1024; i += 256) hist[i] = 0;
    __syncthreads();
    for (int e = s + threadIdx.x; e < e_end; e += 256)
        atomicAdd(&hist[dst[e] >> 8], 1);
    __syncthreads();
    for (int i = threadIdx.x; i < 1024; i += 256) {
        int h = hist[i];
        base[i] = h ? atomicAdd(&btail[i], h) : 0;
        hist[i] = 0;  // reuse as local append counter
    }
    __syncthreads();
    for (int e = s + threadIdx.x; e < e_end; e += 256) {
        int d = dst[e];
        int b = d >> 8;
        int pos = base[b] + atomicAdd(&hist[b], 1);
        pairs[pos] = make_int2(src[e], d);
    }
}

// fused: per-bucket histogram -> deg -> LDS scan -> rp/dinv -> place ssrc.
__global__ __launch_bounds__(256) void k_build(
    const int2* __restrict__ pairs, const int* __restrict__ bbase,
    const int* __restrict__ bcnt, float* __restrict__ dinv,
    int* __restrict__ rp, int* __restrict__ ssrc, int N) {
    __shared__ int h[256];
    __shared__ int sc[256];
    __shared__ int lcnt[256];
    int b = blockIdx.x, t = threadIdx.x;
    h[t] = 0;
    __syncthreads();
    int s = bbase[b], cntb = bcnt[b];
    for (int i = t; i < cntb; i += 256)
        atomicAdd(&h[pairs[s + i].y & 255], 1);
    __syncthreads();
    int d = h[t];
    sc[t] = d;
    lcnt[t] = 0;
    __syncthreads();
    for (int off = 1; off < 256; off <<= 1) {
        int u = (t >= off) ? sc[t - off] : 0;
        __syncthreads();
        sc[t] += u;
        __syncthreads();
    }
    int abs_ex = s + sc[t] - d;   // absolute CSR start for this node
    int node = b * 256 + t;
    if (node < N) {
        rp[node] = abs_ex;
        dinv[node] = (d > 0) ? 1.0f / (float)d : 0.0f;
    }
    sc[t] = abs_ex;
    __syncthreads();
    for (int i = t; i < cntb; i += 256) {
        int2 p = pairs[s + i];
        int local = p.y & 255;
        int pos = sc[local] + atomicAdd(&lcnt[local], 1);
        ssrc[pos] = p.x;
    }
}

// h0[n][0:32] = emb[node_ids[n]][0:32]; 8 threads (float4 each) per node
__global__ void k_emb(const int* __restrict__ ids, const float* __restrict__ emb,
                      float* __restrict__ h0, int n) {
    int t = blockIdx.x * 256 + threadIdx.x;
    int node = t >> 3, q = t & 7;
    if (node >= n) return;
    size_t id = (size_t)ids[node];
    *(float4*)(h0 + (size_t)node * 32 + q * 4) =
        *(const float4*)(emb + id * 32 + q * 4);
}

// mean-agg 32-wide rows: wave per node, 8 edges x 8 lanes(float4) per pass,
// unrolled x2 (16 edges in flight) with independent accumulators.
__global__ void k_agg32(const float* __restrict__ h, const int* __restrict__ rp,
                        const int* __restrict__ ssrc, const float* __restrict__ dinv,
                        float* __restrict__ agg, int n) {
    int node = (blockIdx.x * 256 + threadIdx.x) >> 6;
    int lane = threadIdx.x & 63;
    if (node >= n) return;
    int start = rp[node], end = rp[node + 1];
    int eo = lane >> 3, q = lane & 7;
    const float* hb = h + q * 4;
    float4 a0 = {0.f, 0.f, 0.f, 0.f}, a1 = {0.f, 0.f, 0.f, 0.f};
    int e = start + eo;
    while (e < end - 8) {
        int s0 = ssrc[e], s1 = ssrc[e + 8];
        float4 v0 = *(const float4*)(hb + (size_t)s0 * 32);
        float4 v1 = *(const float4*)(hb + (size_t)s1 * 32);
        a0.x += v0.x; a0.y += v0.y; a0.z += v0.z; a0.w += v0.w;
        a1.x += v1.x; a1.y += v1.y; a1.z += v1.z; a1.w += v1.w;
        e += 16;
    }
    for (; e < end; e += 8) {
        int s = ssrc[e];
        float4 v = *(const float4*)(hb + (size_t)s * 32);
        a0.x += v.x; a0.y += v.y; a0.z += v.z; a0.w += v.w;
    }
    float4 acc = {a0.x + a1.x, a0.y + a1.y, a0.z + a1.z, a0.w + a1.w};
    for (int m = 8; m < 64; m <<= 1) {
        acc.x += __shfl_xor(acc.x, m);
        acc.y += __shfl_xor(acc.y, m);
        acc.z += __shfl_xor(acc.z, m);
        acc.w += __shfl_xor(acc.w, m);
    }
    if (lane < 8) {
        float di = dinv[node];
        float4 o = {acc.x * di, acc.y * di, acc.z * di, acc.w * di};
        *(float4*)(agg + (size_t)node * 32 + q * 4) = o;
    }
}

// mean-agg 64-wide rows: wave per node, 4 edges x 16 lanes(float4) per pass,
// unrolled x4 (16 edges in flight) with independent accumulators.
__global__ void k_agg64(const float* __restrict__ h, const int* __restrict__ rp,
                        const int* __restrict__ ssrc, const float* __restrict__ dinv,
                        float* __restrict__ agg, int n) {
    int node = (blockIdx.x * 256 + threadIdx.x) >> 6;
    int lane = threadIdx.x & 63;
    if (node >= n) return;
    int start = rp[node], end = rp[node + 1];
    int eo = lane >> 4, q = lane & 15;
    const float* hb = h + q * 4;
    float4 a0 = {0.f, 0.f, 0.f, 0.f}, a1 = {0.f, 0.f, 0.f, 0.f};
    float4 a2 = {0.f, 0.f, 0.f, 0.f}, a3 = {0.f, 0.f, 0.f, 0.f};
    int e = start + eo;
    while (e < end - 12) {
        int s0 = ssrc[e], s1 = ssrc[e + 4], s2 = ssrc[e + 8], s3 = ssrc[e + 12];
        float4 v0 = *(const float4*)(hb + (size_t)s0 * 64);
        float4 v1 = *(const float4*)(hb + (size_t)s1 * 64);
        float4 v2 = *(const float4*)(hb + (size_t)s2 * 64);
        float4 v3 = *(const float4*)(hb + (size_t)s3 * 64);
        a0.x += v0.x; a0.y += v0.y; a0.z += v0.z; a0.w += v0.w;
        a1.x += v1.x; a1.y += v1.y; a1.z += v1.z; a1.w += v1.w;
        a2.x += v2.x; a2.y += v2.y; a2.z += v2.z; a2.w += v2.w;
        a3.x += v3.x; a3.y += v3.y; a3.z += v3.z; a3.w += v3.w;
        e += 16;
    }
    for (; e < end; e += 4) {
        int s = ssrc[e];
        float4 v = *(const float4*)(hb + (size_t)s * 64);
        a0.x += v.x; a0.y += v.y; a0.z += v.z; a0.w += v.w;
    }
    float4 acc = {(a0.x + a1.x) + (a2.x + a3.x), (a0.y + a1.y) + (a2.y + a3.y),
                  (a0.z + a1.z) + (a2.z + a3.z), (a0.w + a1.w) + (a2.w + a3.w)};
    for (int m = 16; m < 64; m <<= 1) {
        acc.x += __shfl_xor(acc.x, m);
        acc.y += __shfl_xor(acc.y, m);
        acc.z += __shfl_xor(acc.z, m);
        acc.w += __shfl_xor(acc.w, m);
    }
    if (lane < 16) {
        float di = dinv[node];
        float4 o = {acc.x * di, acc.y * di, acc.z * di, acc.w * di};
        *(float4*)(agg + (size_t)node * 64 + q * 4) = o;
    }
}

// out[n][64] = relu(x[n][:K] @ Ws + a[n][:K] @ Wn + b); thread = node.
template <int K>
__global__ __launch_bounds__(256) void k_dense(
    const float* __restrict__ x, const float* __restrict__ a,
    const float* __restrict__ Wsg, const float* __restrict__ Wng,
    const float* __restrict__ bg, float* __restrict__ out, int n) {
    __shared__ float ws[K * 64];
    __shared__ float wn[K * 64];
    __shared__ float bs[64];
    for (int i = threadIdx.x; i < K * 64; i += 256) { ws[i] = Wsg[i]; wn[i] = Wng[i]; }
    if (threadIdx.x < 64) bs[threadIdx.x] = bg[threadIdx.x];
    __syncthreads();
    int node = blockIdx.x * 256 + threadIdx.x;
    if (node >= n) return;
    float xr[K], ar[K];
#pragma unroll
    for (int q = 0; q < K / 4; ++q) {
        float4 v = *(const float4*)(x + (size_t)node * K + q * 4);
        xr[q * 4 + 0] = v.x; xr[q * 4 + 1] = v.y; xr[q * 4 + 2] = v.z; xr[q * 4 + 3] = v.w;
        float4 u = *(const float4*)(a + (size_t)node * K + q * 4);
        ar[q * 4 + 0] = u.x; ar[q * 4 + 1] = u.y; ar[q * 4 + 2] = u.z; ar[q * 4 + 3] = u.w;
    }
    float* op = out + (size_t)node * 64;
#pragma unroll 1
    for (int jt = 0; jt < 8; ++jt) {
        float acc0 = bs[jt * 8 + 0], acc1 = bs[jt * 8 + 1], acc2 = bs[jt * 8 + 2], acc3 = bs[jt * 8 + 3];
        float acc4 = bs[jt * 8 + 4], acc5 = bs[jt * 8 + 5], acc6 = bs[jt * 8 + 6], acc7 = bs[jt * 8 + 7];
#pragma unroll
        for (int k = 0; k < K; ++k) {
            float4 w0 = *(const float4*)&ws[k * 64 + jt * 8];
            float4 w1 = *(const float4*)&ws[k * 64 + jt * 8 + 4];
            acc0 += xr[k] * w0.x; acc1 += xr[k] * w0.y; acc2 += xr[k] * w0.z; acc3 += xr[k] * w0.w;
            acc4 += xr[k] * w1.x; acc5 += xr[k] * w1.y; acc6 += xr[k] * w1.z; acc7 += xr[k] * w1.w;
            float4 v0 = *(const float4*)&wn[k * 64 + jt * 8];
            float4 v1 = *(const float4*)&wn[k * 64 + jt * 8 + 4];
            acc0 += ar[k] * v0.x; acc1 += ar[k] * v0.y; acc2 += ar[k] * v0.z; acc3 += ar[k] * v0.w;
            acc4 += ar[k] * v1.x; acc5 += ar[k] * v1.y; acc6 += ar[k] * v1.z; acc7 += ar[k] * v1.w;
        }
        float4 o0 = {fmaxf(acc0, 0.f), fmaxf(acc1, 0.f), fmaxf(acc2, 0.f), fmaxf(acc3, 0.f)};
        float4 o1 = {fmaxf(acc4, 0.f), fmaxf(acc5, 0.f), fmaxf(acc6, 0.f), fmaxf(acc7, 0.f)};
        *(float4*)(op + jt * 8) = o0;
        *(float4*)(op + jt * 8 + 4) = o1;
    }
}

// graph boundaries via binary search (graph_ids is sorted)
__global__ void k_bounds(const int* __restrict__ gid, int* __restrict__ starts,
                         int n, int B) {
    int b = blockIdx.x * 256 + threadIdx.x;
    if (b > B) return;
    if (b == B) { starts[B] = n; return; }
    int lo = 0, hi = n;
    while (lo < hi) {
        int mid = (lo + hi) >> 1;
        if (gid[mid] < b) lo = mid + 1; else hi = mid;
    }
    starts[b] = lo;
}

// per-graph mean over node range; block per graph, 4 rows x 64 feats
__global__ void k_pool(const float* __restrict__ h2, const int* __restrict__ starts,
                       float* __restrict__ hg, int B) {
    __shared__ float sm[256];
    int b = blockIdx.x;
    int t = threadIdx.x, j = t & 63, r = t >> 6;
    int s = starts[b], e = starts[b + 1];
    float acc = 0.f;
    for (int nn = s + r; nn < e; nn += 4) acc += h2[(size_t)nn * 64 + j];
    sm[t] = acc;
    __syncthreads();
    if (t < 64) {
        float v = sm[t] + sm[t + 64] + sm[t + 128] + sm[t + 192];
        float cntf = (float)(e - s);
        hg[b * 64 + j] = v / fmaxf(cntf, 1.0f);
    }
}

// scorer: relu(hg @ Ws1 + bs1) @ Ws2 + bs2 ; block per graph, 64 lanes
__global__ void k_score(const float* __restrict__ hg, const float* __restrict__ Ws1,
                        const float* __restrict__ bs1, const float* __restrict__ Ws2,
                        const float* __restrict__ bs2, float* __restrict__ out, int B) {
    int b = blockIdx.x;
    int j = threadIdx.x;  // 64 threads
    const float* hrow = hg + b * 64;
    float acc = bs1[j];
    for (int k = 0; k < 64; ++k) acc += hrow[k] * Ws1[k * 64 + j];
    float t = fmaxf(acc, 0.f) * Ws2[j];
    for (int m = 1; m < 64; m <<= 1) t += __shfl_xor(t, m);
    if (j == 0) out[b] = t + bs2[0];
}

extern "C" void kernel_launch(void* const* d_in, const int* in_sizes, int n_in,
                              void* d_out, int out_size, void* d_ws, size_t ws_size,
                              hipStream_t stream) {
    const int*   node_ids = (const int*)d_in[0];
    const int*   src      = (const int*)d_in[1];
    const int*   dst      = (const int*)d_in[2];
    const int*   gid      = (const int*)d_in[3];
    const float* emb      = (const float*)d_in[4];
    const float* Ws1      = (const float*)d_in[5];
    const float* Wn1      = (const float*)d_in[6];
    const float* b1       = (const float*)d_in[7];
    const float* Ws2      = (const float*)d_in[8];
    const float* Wn2      = (const float*)d_in[9];
    const float* b2       = (const float*)d_in[10];
    const float* Ms1      = (const float*)d_in[11];
    const float* mb1      = (const float*)d_in[12];
    const float* Ms2      = (const float*)d_in[13];
    const float* mb2      = (const float*)d_in[14];
    float* out = (float*)d_out;

    int N = in_sizes[0];
    int E = in_sizes[1];
    int B = out_size;
    int NB = (N + 255) >> 8;          // dst buckets (<=1024)

    char* w = (char*)d_ws;
    size_t off = 0;
    auto take = [&](size_t bytes) -> void* {
        void* p = (void*)(w + off);
        off += (bytes + 255) & ~(size_t)255;
        return p;
    };
    int*   rp     = (int*)take((size_t)(N + 1) * 4);
    float* dinv   = (float*)take((size_t)N * 4);
    int*   ssrc   = (int*)take((size_t)E * 4);
    int*   bcnt   = (int*)take(1024 * 4);
    int*   bbase  = (int*)take(1024 * 4);
    int*   btail  = (int*)take(1024 * 4);
    float* h0     = (float*)take((size_t)N * 64 * 4);   // layer-1 input (stride 32), reused as h2 (stride 64)
    float* h1     = (float*)take((size_t)N * 64 * 4);
    float* agg    = (float*)take((size_t)N * 64 * 4);   // reused: stride 32 then 64
    int*   starts = (int*)take((size_t)(B + 1) * 4);
    float* hg     = (float*)take((size_t)B * 64 * 4);
    int2*  pairs  = (int2*)agg;       // alias: pairs dead before k_agg32 writes agg

    int nbeb = (E + EPB - 1) / EPB;

    hipMemsetAsync(bcnt, 0, (size_t)NB * 4, stream);
    k_bcnt<<<nbeb, 256, 0, stream>>>(dst, bcnt, E);
    k_bscan<<<1, 1024, 0, stream>>>(bcnt, bbase, btail, rp, NB, N, E);
    k_binscatter<<<nbeb, 256, 0, stream>>>(src, dst, btail, pairs, E);
    k_build<<<NB, 256, 0, stream>>>(pairs, bbase, bcnt, dinv, rp, ssrc, N);

    k_emb<<<(N * 8 + 255) / 256, 256, 0, stream>>>(node_ids, emb, h0, N);

    // layer 1: agg over h0 (32-wide), dense 32->64
    k_agg32<<<(N + 3) / 4, 256, 0, stream>>>(h0, rp, ssrc, dinv, agg, N);
    k_dense<32><<<(N + 255) / 256, 256, 0, stream>>>(h0, agg, Ws1, Wn1, b1, h1, N);

    // layer 2: agg over h1 (64-wide), dense 64->64 (h2 reuses h0 buffer)
    k_agg64<<<(N + 3) / 4, 256, 0, stream>>>(h1, rp, ssrc, dinv, agg, N);
    k_dense<64><<<(N + 255) / 256, 256, 0, stream>>>(h1, agg, Ws2, Wn2, b2, h0, N);

    // pooling + scorer
    k_bounds<<<(B + 1 + 255) / 256, 256, 0, stream>>>(gid, starts, N, B);
    k_pool<<<B, 256, 0, stream>>>(h0, starts, hg, B);
    k_score<<<B, 64, 0, stream>>>(hg, Ms1, mb1, Ms2, mb2, out, B);
}

// Round 8
// 719.266 us; speedup vs baseline: 1.0267x; 1.0037x over previous
//
#include <hip/hip_runtime.h>
#include <hip/hip_fp16.h>

// ---------------------------------------------------------------------------
// GraphSAGE (2x SAGEConv mean + mean-pool + MLP scorer).
// CSR build via two-level counting sort (bucket = dst>>8). Aggregation is
// wave-per-node gather, unrolled with independent accumulators (MLP=4).
// Layer-2 gather reads an fp16 shadow of h1 (halves random-line miss traffic,
// the measured 3.8 TB/s wall); accumulation and everything else stays fp32.
// ---------------------------------------------------------------------------

#define EPB 16384  // edges per block in binning kernels

// per-block LDS histogram of bucket sizes -> global bucket counts
__global__ __launch_bounds__(256) void k_bcnt(const int* __restrict__ dst,
                                              int* __restrict__ bcnt, int E) {
    __shared__ int hist[1024];
    for (int i = threadIdx.x; i < 1024; i += 256) hist[i] = 0;
    __syncthreads();
    int s = blockIdx.x * EPB;
    int e_end = min(s + EPB, E);
    for (int e = s + threadIdx.x; e < e_end; e += 256)
        atomicAdd(&hist[dst[e] >> 8], 1);
    __syncthreads();
    for (int i = threadIdx.x; i < 1024; i += 256)
        if (hist[i]) atomicAdd(&bcnt[i], hist[i]);
}

// exclusive scan of bucket counts (NB <= 1024) -> bbase, mutable btail, rp[N]=E
__global__ void k_bscan(const int* __restrict__ bcnt, int* __restrict__ bbase,
                        int* __restrict__ btail, int* __restrict__ rp,
                        int NB, int N, int E) {
    __shared__ int sm[1024];
    int t = threadIdx.x;
    int v = (t < NB) ? bcnt[t] : 0;
    sm[t] = v;
    __syncthreads();
    for (int off = 1; off < 1024; off <<= 1) {
        int u = (t >= off) ? sm[t - off] : 0;
        __syncthreads();
        sm[t] += u;
        __syncthreads();
    }
    if (t < NB) { int ex = sm[t] - v; bbase[t] = ex; btail[t] = ex; }
    if (t == 0) rp[N] = E;
}

// bin (src,dst) pairs into bucket regions; per-block LDS count -> one global
// atomic per (block,bucket) -> appending, line-local writes
__global__ __launch_bounds__(256) void k_binscatter(
    const int* __restrict__ src, const int* __restrict__ dst,
    int* __restrict__ btail, int2* __restrict__ pairs, int E) {
    __shared__ int hist[1024];
    __shared__ int base[1024];
    int s = blockIdx.x * EPB;
    int e_end = min(s + EPB, E);
    for (int i = threadIdx.x; i < 1024; i += 256) hist[i] = 0;
    __syncthreads();
    for (int e = s + threadIdx.x; e < e_end; e += 256)
        atomicAdd(&hist[dst[e] >> 8], 1);
    __syncthreads();
    for (int i = threadIdx.x; i < 1024; i += 256) {
        int h = hist[i];
        base[i] = h ? atomicAdd(&btail[i], h) : 0;
        hist[i] = 0;  // reuse as local append counter
    }
    __syncthreads();
    for (int e = s + threadIdx.x; e < e_end; e += 256) {
        int d = dst[e];
        int b = d >> 8;
        int pos = base[b] + atomicAdd(&hist[b], 1);
        pairs[pos] = make_int2(src[e], d);
    }
}

// fused: per-bucket histogram -> deg -> LDS scan -> rp/dinv -> place ssrc.
__global__ __launch_bounds__(256) void k_build(
    const int2* __restrict__ pairs, const int* __restrict__ bbase,
    const int* __restrict__ bcnt, float* __restrict__ dinv,
    int* __restrict__ rp, int* __restrict__ ssrc, int N) {
    __shared__ int h[256];
    __shared__ int sc[256];
    __shared__ int lcnt[256];
    int b = blockIdx.x, t = threadIdx.x;
    h[t] = 0;
    __syncthreads();
    int s = bbase[b], cntb = bcnt[b];
    for (int i = t; i < cntb; i += 256)
        atomicAdd(&h[pairs[s + i].y & 255], 1);
    __syncthreads();
    int d = h[t];
    sc[t] = d;
    lcnt[t] = 0;
    __syncthreads();
    for (int off = 1; off < 256; off <<= 1) {
        int u = (t >= off) ? sc[t - off] : 0;
        __syncthreads();
        sc[t] += u;
        __syncthreads();
    }
    int abs_ex = s + sc[t] - d;   // absolute CSR start for this node
    int node = b * 256 + t;
    if (node < N) {
        rp[node] = abs_ex;
        dinv[node] = (d > 0) ? 1.0f / (float)d : 0.0f;
    }
    sc[t] = abs_ex;
    __syncthreads();
    for (int i = t; i < cntb; i += 256) {
        int2 p = pairs[s + i];
        int local = p.y & 255;
        int pos = sc[local] + atomicAdd(&lcnt[local], 1);
        ssrc[pos] = p.x;
    }
}

// h0[n][0:32] = emb[node_ids[n]][0:32]; 8 threads (float4 each) per node
__global__ void k_emb(const int* __restrict__ ids, const float* __restrict__ emb,
                      float* __restrict__ h0, int n) {
    int t = blockIdx.x * 256 + threadIdx.x;
    int node = t >> 3, q = t & 7;
    if (node >= n) return;
    size_t id = (size_t)ids[node];
    *(float4*)(h0 + (size_t)node * 32 + q * 4) =
        *(const float4*)(emb + id * 32 + q * 4);
}

// mean-agg 32-wide fp32 rows: wave per node, 8 edges x 8 lanes(float4) per
// pass, unrolled x2 (16 edges in flight) with independent accumulators.
__global__ void k_agg32(const float* __restrict__ h, const int* __restrict__ rp,
                        const int* __restrict__ ssrc, const float* __restrict__ dinv,
                        float* __restrict__ agg, int n) {
    int node = (blockIdx.x * 256 + threadIdx.x) >> 6;
    int lane = threadIdx.x & 63;
    if (node >= n) return;
    int start = rp[node], end = rp[node + 1];
    int eo = lane >> 3, q = lane & 7;
    const float* hb = h + q * 4;
    float4 a0 = {0.f, 0.f, 0.f, 0.f}, a1 = {0.f, 0.f, 0.f, 0.f};
    int e = start + eo;
    while (e < end - 8) {
        int s0 = ssrc[e], s1 = ssrc[e + 8];
        float4 v0 = *(const float4*)(hb + (size_t)s0 * 32);
        float4 v1 = *(const float4*)(hb + (size_t)s1 * 32);
        a0.x += v0.x; a0.y += v0.y; a0.z += v0.z; a0.w += v0.w;
        a1.x += v1.x; a1.y += v1.y; a1.z += v1.z; a1.w += v1.w;
        e += 16;
    }
    for (; e < end; e += 8) {
        int s = ssrc[e];
        float4 v = *(const float4*)(hb + (size_t)s * 32);
        a0.x += v.x; a0.y += v.y; a0.z += v.z; a0.w += v.w;
    }
    float4 acc = {a0.x + a1.x, a0.y + a1.y, a0.z + a1.z, a0.w + a1.w};
    for (int m = 8; m < 64; m <<= 1) {
        acc.x += __shfl_xor(acc.x, m);
        acc.y += __shfl_xor(acc.y, m);
        acc.z += __shfl_xor(acc.z, m);
        acc.w += __shfl_xor(acc.w, m);
    }
    if (lane < 8) {
        float di = dinv[node];
        float4 o = {acc.x * di, acc.y * di, acc.z * di, acc.w * di};
        *(float4*)(agg + (size_t)node * 32 + q * 4) = o;
    }
}

__device__ inline void acc8h(uint4 u, float4& lo, float4& hi) {
    const __half2* ph = (const __half2*)&u;
    float2 f0 = __half22float2(ph[0]);
    float2 f1 = __half22float2(ph[1]);
    float2 f2 = __half22float2(ph[2]);
    float2 f3 = __half22float2(ph[3]);
    lo.x += f0.x; lo.y += f0.y; lo.z += f1.x; lo.w += f1.y;
    hi.x += f2.x; hi.y += f2.y; hi.z += f3.x; hi.w += f3.y;
}

// mean-agg 64-wide fp16 rows (128B): wave per node, 8 edges x 8 lanes(16B)
// per pass, unrolled x2 (16 edges in flight). fp32 accumulate.
__global__ void k_agg64h(const __half* __restrict__ h, const int* __restrict__ rp,
                         const int* __restrict__ ssrc, const float* __restrict__ dinv,
                         float* __restrict__ agg, int n) {
    int node = (blockIdx.x * 256 + threadIdx.x) >> 6;
    int lane = threadIdx.x & 63;
    if (node >= n) return;
    int start = rp[node], end = rp[node + 1];
    int eo = lane >> 3, q = lane & 7;
    const __half* hb = h + q * 8;   // 8 halves = 16B per lane
    float4 lo0 = {0.f,0.f,0.f,0.f}, hi0 = {0.f,0.f,0.f,0.f};
    float4 lo1 = {0.f,0.f,0.f,0.f}, hi1 = {0.f,0.f,0.f,0.f};
    int e = start + eo;
    while (e < end - 8) {
        int s0 = ssrc[e], s1 = ssrc[e + 8];
        uint4 u0 = *(const uint4*)(hb + (size_t)s0 * 64);
        uint4 u1 = *(const uint4*)(hb + (size_t)s1 * 64);
        acc8h(u0, lo0, hi0);
        acc8h(u1, lo1, hi1);
        e += 16;
    }
    for (; e < end; e += 8) {
        int s = ssrc[e];
        uint4 u = *(const uint4*)(hb + (size_t)s * 64);
        acc8h(u, lo0, hi0);
    }
    float4 lo = {lo0.x + lo1.x, lo0.y + lo1.y, lo0.z + lo1.z, lo0.w + lo1.w};
    float4 hi = {hi0.x + hi1.x, hi0.y + hi1.y, hi0.z + hi1.z, hi0.w + hi1.w};
    for (int m = 8; m < 64; m <<= 1) {
        lo.x += __shfl_xor(lo.x, m); lo.y += __shfl_xor(lo.y, m);
        lo.z += __shfl_xor(lo.z, m); lo.w += __shfl_xor(lo.w, m);
        hi.x += __shfl_xor(hi.x, m); hi.y += __shfl_xor(hi.y, m);
        hi.z += __shfl_xor(hi.z, m); hi.w += __shfl_xor(hi.w, m);
    }
    if (lane < 8) {
        float di = dinv[node];
        float4 oL = {lo.x * di, lo.y * di, lo.z * di, lo.w * di};
        float4 oH = {hi.x * di, hi.y * di, hi.z * di, hi.w * di};
        float* op = agg + (size_t)node * 64 + q * 8;
        *(float4*)op = oL;
        *(float4*)(op + 4) = oH;
    }
}

// out[n][64] = relu(x[n][:K] @ Ws + a[n][:K] @ Wn + b); thread = node.
// Optionally also writes an fp16 shadow copy (for the next gather pass).
template <int K>
__global__ __launch_bounds__(256) void k_dense(
    const float* __restrict__ x, const float* __restrict__ a,
    const float* __restrict__ Wsg, const float* __restrict__ Wng,
    const float* __restrict__ bg, float* __restrict__ out,
    __half* __restrict__ outh, int n) {
    __shared__ float ws[K * 64];
    __shared__ float wn[K * 64];
    __shared__ float bs[64];
    for (int i = threadIdx.x; i < K * 64; i += 256) { ws[i] = Wsg[i]; wn[i] = Wng[i]; }
    if (threadIdx.x < 64) bs[threadIdx.x] = bg[threadIdx.x];
    __syncthreads();
    int node = blockIdx.x * 256 + threadIdx.x;
    if (node >= n) return;
    float xr[K], ar[K];
#pragma unroll
    for (int q = 0; q < K / 4; ++q) {
        float4 v = *(const float4*)(x + (size_t)node * K + q * 4);
        xr[q * 4 + 0] = v.x; xr[q * 4 + 1] = v.y; xr[q * 4 + 2] = v.z; xr[q * 4 + 3] = v.w;
        float4 u = *(const float4*)(a + (size_t)node * K + q * 4);
        ar[q * 4 + 0] = u.x; ar[q * 4 + 1] = u.y; ar[q * 4 + 2] = u.z; ar[q * 4 + 3] = u.w;
    }
    float* op = out + (size_t)node * 64;
    __half* oph = outh ? (outh + (size_t)node * 64) : nullptr;
#pragma unroll 1
    for (int jt = 0; jt < 8; ++jt) {
        float acc0 = bs[jt * 8 + 0], acc1 = bs[jt * 8 + 1], acc2 = bs[jt * 8 + 2], acc3 = bs[jt * 8 + 3];
        float acc4 = bs[jt * 8 + 4], acc5 = bs[jt * 8 + 5], acc6 = bs[jt * 8 + 6], acc7 = bs[jt * 8 + 7];
#pragma unroll
        for (int k = 0; k < K; ++k) {
            float4 w0 = *(const float4*)&ws[k * 64 + jt * 8];
            float4 w1 = *(const float4*)&ws[k * 64 + jt * 8 + 4];
            acc0 += xr[k] * w0.x; acc1 += xr[k] * w0.y; acc2 += xr[k] * w0.z; acc3 += xr[k] * w0.w;
            acc4 += xr[k] * w1.x; acc5 += xr[k] * w1.y; acc6 += xr[k] * w1.z; acc7 += xr[k] * w1.w;
            float4 v0 = *(const float4*)&wn[k * 64 + jt * 8];
            float4 v1 = *(const float4*)&wn[k * 64 + jt * 8 + 4];
            acc0 += ar[k] * v0.x; acc1 += ar[k] * v0.y; acc2 += ar[k] * v0.z; acc3 += ar[k] * v0.w;
            acc4 += ar[k] * v1.x; acc5 += ar[k] * v1.y; acc6 += ar[k] * v1.z; acc7 += ar[k] * v1.w;
        }
        float4 o0 = {fmaxf(acc0, 0.f), fmaxf(acc1, 0.f), fmaxf(acc2, 0.f), fmaxf(acc3, 0.f)};
        float4 o1 = {fmaxf(acc4, 0.f), fmaxf(acc5, 0.f), fmaxf(acc6, 0.f), fmaxf(acc7, 0.f)};
        *(float4*)(op + jt * 8) = o0;
        *(float4*)(op + jt * 8 + 4) = o1;
        if (oph) {
            __half2 p0 = __floats2half2_rn(o0.x, o0.y);
            __half2 p1 = __floats2half2_rn(o0.z, o0.w);
            __half2 p2 = __floats2half2_rn(o1.x, o1.y);
            __half2 p3 = __floats2half2_rn(o1.z, o1.w);
            uint4 pk;
            pk.x = *(unsigned int*)&p0; pk.y = *(unsigned int*)&p1;
            pk.z = *(unsigned int*)&p2; pk.w = *(unsigned int*)&p3;
            *(uint4*)(oph + jt * 8) = pk;
        }
    }
}

// graph boundaries via binary search (graph_ids is sorted)
__global__ void k_bounds(const int* __restrict__ gid, int* __restrict__ starts,
                         int n, int B) {
    int b = blockIdx.x * 256 + threadIdx.x;
    if (b > B) return;
    if (b == B) { starts[B] = n; return; }
    int lo = 0, hi = n;
    while (lo < hi) {
        int mid = (lo + hi) >> 1;
        if (gid[mid] < b) lo = mid + 1; else hi = mid;
    }
    starts[b] = lo;
}

// per-graph mean over node range; block per graph, 4 rows x 64 feats
__global__ void k_pool(const float* __restrict__ h2, const int* __restrict__ starts,
                       float* __restrict__ hg, int B) {
    __shared__ float sm[256];
    int b = blockIdx.x;
    int t = threadIdx.x, j = t & 63, r = t >> 6;
    int s = starts[b], e = starts[b + 1];
    float acc = 0.f;
    for (int nn = s + r; nn < e; nn += 4) acc += h2[(size_t)nn * 64 + j];
    sm[t] = acc;
    __syncthreads();
    if (t < 64) {
        float v = sm[t] + sm[t + 64] + sm[t + 128] + sm[t + 192];
        float cntf = (float)(e - s);
        hg[b * 64 + j] = v / fmaxf(cntf, 1.0f);
    }
}

// scorer: relu(hg @ Ws1 + bs1) @ Ws2 + bs2 ; block per graph, 64 lanes
__global__ void k_score(const float* __restrict__ hg, const float* __restrict__ Ws1,
                        const float* __restrict__ bs1, const float* __restrict__ Ws2,
                        const float* __restrict__ bs2, float* __restrict__ out, int B) {
    int b = blockIdx.x;
    int j = threadIdx.x;  // 64 threads
    const float* hrow = hg + b * 64;
    float acc = bs1[j];
    for (int k = 0; k < 64; ++k) acc += hrow[k] * Ws1[k * 64 + j];
    float t = fmaxf(acc, 0.f) * Ws2[j];
    for (int m = 1; m < 64; m <<= 1) t += __shfl_xor(t, m);
    if (j == 0) out[b] = t + bs2[0];
}

extern "C" void kernel_launch(void* const* d_in, const int* in_sizes, int n_in,
                              void* d_out, int out_size, void* d_ws, size_t ws_size,
                              hipStream_t stream) {
    const int*   node_ids = (const int*)d_in[0];
    const int*   src      = (const int*)d_in[1];
    const int*   dst      = (const int*)d_in[2];
    const int*   gid      = (const int*)d_in[3];
    const float* emb      = (const float*)d_in[4];
    const float* Ws1      = (const float*)d_in[5];
    const float* Wn1      = (const float*)d_in[6];
    const float* b1       = (const float*)d_in[7];
    const float* Ws2      = (const float*)d_in[8];
    const float* Wn2      = (const float*)d_in[9];
    const float* b2       = (const float*)d_in[10];
    const float* Ms1      = (const float*)d_in[11];
    const float* mb1      = (const float*)d_in[12];
    const float* Ms2      = (const float*)d_in[13];
    const float* mb2      = (const float*)d_in[14];
    float* out = (float*)d_out;

    int N = in_sizes[0];
    int E = in_sizes[1];
    int B = out_size;
    int NB = (N + 255) >> 8;          // dst buckets (<=1024)

    char* w = (char*)d_ws;
    size_t off = 0;
    auto take = [&](size_t bytes) -> void* {
        void* p = (void*)(w + off);
        off += (bytes + 255) & ~(size_t)255;
        return p;
    };
    int*    rp     = (int*)take((size_t)(N + 1) * 4);
    float*  dinv   = (float*)take((size_t)N * 4);
    int*    ssrc   = (int*)take((size_t)E * 4);
    int*    bcnt   = (int*)take(1024 * 4);
    int*    bbase  = (int*)take(1024 * 4);
    int*    btail  = (int*)take(1024 * 4);
    float*  h0     = (float*)take((size_t)N * 64 * 4);  // layer-1 input (stride 32), reused as h2 (stride 64)
    float*  h1     = (float*)take((size_t)N * 64 * 4);
    float*  agg    = (float*)take((size_t)N * 64 * 4);  // reused: stride 32 then 64
    __half* h1h    = (__half*)take((size_t)N * 64 * 2); // fp16 shadow of h1
    int*    starts = (int*)take((size_t)(B + 1) * 4);
    float*  hg     = (float*)take((size_t)B * 64 * 4);
    int2*   pairs  = (int2*)agg;      // alias: pairs dead before k_agg32 writes agg

    int nbeb = (E + EPB - 1) / EPB;

    hipMemsetAsync(bcnt, 0, (size_t)NB * 4, stream);
    k_bcnt<<<nbeb, 256, 0, stream>>>(dst, bcnt, E);
    k_bscan<<<1, 1024, 0, stream>>>(bcnt, bbase, btail, rp, NB, N, E);
    k_binscatter<<<nbeb, 256, 0, stream>>>(src, dst, btail, pairs, E);
    k_build<<<NB, 256, 0, stream>>>(pairs, bbase, bcnt, dinv, rp, ssrc, N);

    k_emb<<<(N * 8 + 255) / 256, 256, 0, stream>>>(node_ids, emb, h0, N);

    // layer 1: agg over h0 (fp32, 32-wide), dense 32->64 (+fp16 shadow of h1)
    k_agg32<<<(N + 3) / 4, 256, 0, stream>>>(h0, rp, ssrc, dinv, agg, N);
    k_dense<32><<<(N + 255) / 256, 256, 0, stream>>>(h0, agg, Ws1, Wn1, b1, h1, h1h, N);

    // layer 2: agg over h1h (fp16, 64-wide), dense 64->64 (h2 reuses h0 buffer)
    k_agg64h<<<(N + 3) / 4, 256, 0, stream>>>(h1h, rp, ssrc, dinv, agg, N);
    k_dense<64><<<(N + 255) / 256, 256, 0, stream>>>(h1, agg, Ws2, Wn2, b2, h0, nullptr, N);

    // pooling + scorer
    k_bounds<<<(B + 1 + 255) / 256, 256, 0, stream>>>(gid, starts, N, B);
    k_pool<<<B, 256, 0, stream>>>(h0, starts, hg, B);
    k_score<<<B, 64, 0, stream>>>(hg, Ms1, mb1, Ms2, mb2, out, B);
}